// Round 7
// baseline (267.157 us; speedup 1.0000x reference)
//
#include <hip/hip_runtime.h>
#include <hip/hip_bf16.h>

// DiffAttn: B=4, S=4096, EMB=1024, D=128
//   Q = X@Wq+bq (256 cols = Q1|Q2), K likewise, V = X@Wv+bv (128)
//   out = softmax(Q1K1^T/sqrt(D))@V - lam*softmax(Q2K2^T/sqrt(D))@V
// attn v4: 256-thread blocks (4 waves = 2 q-sub x 2 branches, 64 q/block),
// 2 independent blocks/CU (decoupled barrier domains); rotation-swizzled
// K/V LDS layouts (conflict-free reads AND writes); s_setprio around MFMA;
// raw v_exp_f32 softmax in registers; Vt written directly by proj.

typedef __attribute__((ext_vector_type(8))) short bf16x8;    // 8 bf16
typedef __attribute__((ext_vector_type(4))) float f32x4;
typedef __attribute__((ext_vector_type(16))) float f32x16;   // 32x32 C/D

#define MFMA16(a, b, c) __builtin_amdgcn_mfma_f32_16x16x32_bf16((a), (b), (c), 0, 0, 0)
#define MFMA32(a, b, c) __builtin_amdgcn_mfma_f32_32x32x16_bf16((a), (b), (c), 0, 0, 0)

__device__ __forceinline__ unsigned short f2bf(float x) {
    union { float f; unsigned u; } v; v.f = x;   // RNE float->bf16
    return (unsigned short)((v.u + 0x7FFFu + ((v.u >> 16) & 1u)) >> 16);
}
__device__ __forceinline__ unsigned pk2bf(float a, float b) {   // v_cvt_pk_bf16_f32
    __hip_bfloat162 h = __float22bfloat162_rn(float2{a, b});
    union { __hip_bfloat162 h2; unsigned u; } cv; cv.h2 = h;
    return cv.u;
}
__device__ __forceinline__ float fexp2(float x) {   // raw v_exp_f32: D = 2^S0
    float r; asm("v_exp_f32 %0, %1" : "=v"(r) : "v"(x)); return r;
}

// ---------------- W transpose + bf16 convert: Wt[640][1024] ----------------
__global__ __launch_bounds__(256) void wtrans_kernel(
    const float* __restrict__ Wq, const float* __restrict__ Wk,
    const float* __restrict__ Wv, unsigned short* __restrict__ Wt) {
    int tid = blockIdx.x * 256 + threadIdx.x;   // 640*1024 total
    int k = tid & 1023, n = tid >> 10;
    float v;
    if (n < 256)      v = Wq[k * 256 + n];
    else if (n < 512) v = Wk[k * 256 + (n - 256)];
    else              v = Wv[k * 128 + (n - 512)];
    Wt[tid] = f2bf(v);
}

// ---------------- QKV projection GEMM ----------------
// blockIdx.y = 0,1 -> Q (scaled); 2,3 -> K; 4 -> V (written TRANSPOSED to Vt)
__global__ __launch_bounds__(256) void proj_kernel(
    const float* __restrict__ X, const unsigned short* __restrict__ Wt,
    const float* __restrict__ bq, const float* __restrict__ bk,
    const float* __restrict__ bv,
    unsigned short* __restrict__ Qs, unsigned short* __restrict__ Kb,
    unsigned short* __restrict__ Vt) {
    __shared__ alignas(16) char lds[16384];   // Xt[128][32]bf16 @0, Wtile @8192
    const int nt = blockIdx.y;
    const int m0 = blockIdx.x * 128;
    const int t = threadIdx.x, w = t >> 6, l = t & 63, c = l & 15, g = l >> 4;
    const int wm = w >> 1, wn = w & 1;
    const unsigned short* Wrow = Wt + (long)(nt * 128) * 1024;

    f32x4 acc[4][4];
    const f32x4 fz = {0.f, 0.f, 0.f, 0.f};
#pragma unroll
    for (int i = 0; i < 4; i++)
#pragma unroll
        for (int j = 0; j < 4; j++) acc[i][j] = fz;

    const int srow = t >> 1, sh = t & 1;
    const int sswz = (srow & 7) << 4;
    for (int k0 = 0; k0 < 1024; k0 += 32) {
        const float* xs = X + (long)(m0 + srow) * 1024 + k0 + sh * 16;
        float4 f0 = *(const float4*)(xs + 0);
        float4 f1 = *(const float4*)(xs + 4);
        float4 f2 = *(const float4*)(xs + 8);
        float4 f3 = *(const float4*)(xs + 12);
        const unsigned short* wsc = Wrow + (long)srow * 1024 + k0 + sh * 16;
        uint4 w0 = *(const uint4*)(wsc + 0);
        uint4 w1 = *(const uint4*)(wsc + 8);
        uint4 xa, xb;
        xa.x = pk2bf(f0.x, f0.y); xa.y = pk2bf(f0.z, f0.w);
        xa.z = pk2bf(f1.x, f1.y); xa.w = pk2bf(f1.z, f1.w);
        xb.x = pk2bf(f2.x, f2.y); xb.y = pk2bf(f2.z, f2.w);
        xb.z = pk2bf(f3.x, f3.y); xb.w = pk2bf(f3.z, f3.w);
        int base = srow * 64 + sh * 32;
        *(uint4*)(lds + ((base + 0) ^ sswz)) = xa;
        *(uint4*)(lds + ((base + 16) ^ sswz)) = xb;
        *(uint4*)(lds + 8192 + ((base + 0) ^ sswz)) = w0;
        *(uint4*)(lds + 8192 + ((base + 16) ^ sswz)) = w1;
        __syncthreads();

        bf16x8 af[4];
#pragma unroll
        for (int am = 0; am < 4; am++) {
            int r_ = wm * 64 + am * 16 + c;
            af[am] = *(const bf16x8*)(lds + ((r_ * 64 + g * 16) ^ ((c & 7) << 4)));
        }
#pragma unroll
        for (int bn = 0; bn < 4; bn++) {
            int r_ = wn * 64 + bn * 16 + c;
            bf16x8 bfr = *(const bf16x8*)(lds + 8192 + ((r_ * 64 + g * 16) ^ ((c & 7) << 4)));
#pragma unroll
            for (int am = 0; am < 4; am++) acc[am][bn] = MFMA16(af[am], bfr, acc[am][bn]);
        }
        __syncthreads();
    }

    // Q scale folds 1/sqrt(128) AND log2(e) so attn softmax is pure exp2.
    const float QSCALE = 0.08838834764831845f * 1.4426950408889634f;
    if (nt < 4) {
        const float* bias; float scale; unsigned short* outp; int ocol0, boff;
        if (nt < 2) { bias = bq; boff = nt * 128;       scale = QSCALE; outp = Qs; ocol0 = nt * 128; }
        else        { bias = bk; boff = (nt - 2) * 128; scale = 1.0f;   outp = Kb; ocol0 = (nt - 2) * 128; }
#pragma unroll
        for (int bn = 0; bn < 4; bn++) {
            int ncol = wn * 64 + bn * 16 + c;
            float bb = bias[boff + ncol];
#pragma unroll
            for (int am = 0; am < 4; am++) {
#pragma unroll
                for (int r = 0; r < 4; r++) {
                    long row = m0 + wm * 64 + am * 16 + 4 * g + r;
                    outp[row * 256 + ocol0 + ncol] = f2bf((acc[am][bn][r] + bb) * scale);
                }
            }
        }
    } else {
        // V: write transposed Vt[b][128 d][4096 s]
#pragma unroll
        for (int bn = 0; bn < 4; bn++) {
            int ncol = wn * 64 + bn * 16 + c;
            float bb = bv[ncol];
            unsigned short* vcol = Vt + ((long)((m0 >> 12) * 128 + ncol) << 12);
#pragma unroll
            for (int am = 0; am < 4; am++) {
#pragma unroll
                for (int r = 0; r < 4; r++) {
                    int ss = (m0 & 4095) + wm * 64 + am * 16 + 4 * g + r;
                    vcol[ss] = f2bf(acc[am][bn][r] + bb);
                }
            }
        }
    }
}

// ---------------- flash diff-attention v4 ----------------
// 256 threads = 4 waves = 2 q-subblocks x 2 branches. 64 queries/block.
// grid = 256*nsplit (2 blocks/CU at nsplit=2) with XCD-grouped decode.
// LDS double-buffered {K1 8K | K2 8K | V 8K} x2 = 48K. Rotation swizzle:
//   K: addr = r*256 + ((c + r*16) & 255)   (conflict-free wr+rd)
//   V: addr = r*64  + ((c + (r>>1)*16) & 63)
__global__ __launch_bounds__(256) void attn2_kernel(
    const unsigned short* __restrict__ Qs, const unsigned short* __restrict__ Kb,
    const unsigned short* __restrict__ Vt,
    float* __restrict__ Po, float* __restrict__ Ps, int nsplit, int ks) {
    __shared__ alignas(16) char lds[49152];
    const int t = threadIdx.x;
    const int w = t >> 6, l = t & 63, r31 = l & 31, hi = l >> 5;
    const int wq = w >> 1, br = w & 1;

    const int total = gridDim.x;
    const int lin = (blockIdx.x & 7) * (total >> 3) + (blockIdx.x >> 3);
    const int grp = lin >> 6, qb = lin & 63;   // 64 q-blocks per (b,split) group
    const int b = grp / nsplit, split = grp % nsplit;

    const long qrow = (long)b * 4096 + qb * 64 + wq * 32 + r31;
    bf16x8 qf[8];
    const unsigned short* Qp = Qs + qrow * 256 + br * 128 + hi * 8;
#pragma unroll
    for (int ds = 0; ds < 8; ds++) qf[ds] = *(const bf16x8*)(Qp + ds * 16);

    f32x16 o[4];
    const f32x16 oz = {};
#pragma unroll
    for (int dt = 0; dt < 4; dt++) o[dt] = oz;
    float m = -1e30f, s = 0.f;

    // --- staging maps (256 threads) ---
    // K: thread -> row=t>>3 (0-31), seg=t&7 (64B of the 512B K1|K2 row)
    const int krow = t >> 3, kseg = t & 7;
    const int khalf = kseg >> 2, kcb = (kseg & 3) * 64;
    int kw[4];
#pragma unroll
    for (int j = 0; j < 4; j++)
        kw[j] = khalf * 8192 + krow * 256 + ((kcb + j * 16 + (krow << 4)) & 255);
    // V: thread -> row=t>>1 (0-127), half=t&1 (32B)
    const int vrow = t >> 1, vhalf = t & 1;
    int vw[2];
#pragma unroll
    for (int j = 0; j < 2; j++)
        vw[j] = 16384 + vrow * 64 + ((vhalf * 32 + j * 16 + ((vrow >> 1) << 4)) & 63);
    const unsigned short* vsrc = Vt + (((long)b * 128 + vrow) << 12) + vhalf * 16;
    const long kbb = (long)b * 4096;

    const int kb0 = split * ks, kend = kb0 + ks;
    uint4 kA, kB, kC, kD, vA, vB;
#define LOADTILE(KN)                                                           \
    {                                                                          \
        const unsigned short* kp = Kb + (kbb + (KN) + krow) * 256 + kseg * 32; \
        kA = *(const uint4*)(kp);                                              \
        kB = *(const uint4*)(kp + 8);                                          \
        kC = *(const uint4*)(kp + 16);                                         \
        kD = *(const uint4*)(kp + 24);                                         \
        const unsigned short* vp = vsrc + (KN);                                \
        vA = *(const uint4*)(vp);                                              \
        vB = *(const uint4*)(vp + 8);                                          \
    }
#define WRITETILE(BUF)                                                         \
    {                                                                          \
        char* bb_ = lds + (BUF)*24576;                                         \
        *(uint4*)(bb_ + kw[0]) = kA;                                           \
        *(uint4*)(bb_ + kw[1]) = kB;                                           \
        *(uint4*)(bb_ + kw[2]) = kC;                                           \
        *(uint4*)(bb_ + kw[3]) = kD;                                           \
        *(uint4*)(bb_ + vw[0]) = vA;                                           \
        *(uint4*)(bb_ + vw[1]) = vB;                                           \
    }

    // --- read offsets (loop-invariant) ---
    int kro[8];
#pragma unroll
    for (int ds = 0; ds < 8; ds++)
        kro[ds] = br * 8192 + r31 * 256 + ((ds * 32 + hi * 16 + (r31 << 4)) & 255);
    int vro0[4], vro1[4];
#pragma unroll
    for (int dt = 0; dt < 4; dt++) {
        int vr = dt * 32 + r31;
        vro0[dt] = 16384 + vr * 64 + ((hi * 16 + ((vr >> 1) << 4)) & 63);
        vro1[dt] = 16384 + vr * 64 + ((32 + hi * 16 + ((vr >> 1) << 4)) & 63);
    }

    LOADTILE(kb0);
    WRITETILE(0);
    {
        int kn = (kb0 + 32 < kend) ? kb0 + 32 : kb0;
        LOADTILE(kn);
    }
    int cur = 0;

    for (int kb = kb0; kb < kend; kb += 32) {
        __syncthreads();
        if (kb + 32 < kend) {
            WRITETILE(cur ^ 1);
            int kn = (kb + 64 < kend) ? kb + 64 : kb0;
            LOADTILE(kn);
        }
        const char* bufp = lds + cur * 24576;

        // ---- QK^T: P^T[key][q], two independent 4-deep chains ----
        f32x16 pa = oz, pb_ = oz;
        __builtin_amdgcn_s_setprio(1);
#pragma unroll
        for (int ds = 0; ds < 4; ds++) {
            bf16x8 kfa = *(const bf16x8*)(bufp + kro[ds]);
            bf16x8 kfb = *(const bf16x8*)(bufp + kro[ds + 4]);
            pa = MFMA32(kfa, qf[ds], pa);
            pb_ = MFMA32(kfb, qf[ds + 4], pb_);
        }
        __builtin_amdgcn_s_setprio(0);
        f32x16 p;
#pragma unroll
        for (int i = 0; i < 16; i++) p[i] = pa[i] + pb_[i];

        // ---- in-register softmax (exp2 domain; defer-max THR=8) ----
        float x0 = fmaxf(fmaxf(p[0], p[1]), fmaxf(p[2], p[3]));
        float x1 = fmaxf(fmaxf(p[4], p[5]), fmaxf(p[6], p[7]));
        float x2 = fmaxf(fmaxf(p[8], p[9]), fmaxf(p[10], p[11]));
        float x3 = fmaxf(fmaxf(p[12], p[13]), fmaxf(p[14], p[15]));
        float lmx = fmaxf(fmaxf(x0, x1), fmaxf(x2, x3));
        lmx = fmaxf(lmx, __shfl_xor(lmx, 32));
        if (__any(lmx > m + 8.f)) {
            float mn = fmaxf(m, lmx);
            float al = fexp2(m - mn);
            s *= al; m = mn;
#pragma unroll
            for (int dt = 0; dt < 4; dt++) o[dt] *= al;
        }
        float pe[16];
#pragma unroll
        for (int i = 0; i < 16; i++) pe[i] = fexp2(p[i] - m);
        float s0 = (pe[0] + pe[1]) + (pe[2] + pe[3]);
        float s1 = (pe[4] + pe[5]) + (pe[6] + pe[7]);
        float s2 = (pe[8] + pe[9]) + (pe[10] + pe[11]);
        float s3 = (pe[12] + pe[13]) + (pe[14] + pe[15]);
        float ps_ = (s0 + s1) + (s2 + s3);
        ps_ += __shfl_xor(ps_, 32);
        s += ps_;

        // ---- P -> PV B-fragments (cvt_pk + permlane32_swap) ----
        unsigned cA = pk2bf(pe[0], pe[1]), cB = pk2bf(pe[2], pe[3]);
        unsigned cC = pk2bf(pe[4], pe[5]), cD = pk2bf(pe[6], pe[7]);
        asm volatile("v_permlane32_swap_b32 %0, %1" : "+v"(cA), "+v"(cC));
        asm volatile("v_permlane32_swap_b32 %0, %1" : "+v"(cB), "+v"(cD));
        unsigned dA = pk2bf(pe[8], pe[9]), dB = pk2bf(pe[10], pe[11]);
        unsigned dC = pk2bf(pe[12], pe[13]), dD = pk2bf(pe[14], pe[15]);
        asm volatile("v_permlane32_swap_b32 %0, %1" : "+v"(dA), "+v"(dC));
        asm volatile("v_permlane32_swap_b32 %0, %1" : "+v"(dB), "+v"(dD));
        union { uint4 u; bf16x8 v; } pb0, pb1;
        pb0.u = uint4{cA, cB, cC, cD};   // keys 0-15
        pb1.u = uint4{dA, dB, dC, dD};   // keys 16-31

        // ---- PV: O^T[d][q] += V^T-frag x PB ----
        __builtin_amdgcn_s_setprio(1);
#pragma unroll
        for (int dt = 0; dt < 4; dt++) {
            bf16x8 vf0 = *(const bf16x8*)(bufp + vro0[dt]);
            bf16x8 vf1 = *(const bf16x8*)(bufp + vro1[dt]);
            o[dt] = MFMA32(vf0, pb0.v, o[dt]);
            o[dt] = MFMA32(vf1, pb1.v, o[dt]);
        }
        __builtin_amdgcn_s_setprio(0);
        cur ^= 1;
    }

    // ---- epilogue: per-branch partials ----
    float* po = Po + ((qrow * nsplit + split) * 2 + br) * 128;
#pragma unroll
    for (int dt = 0; dt < 4; dt++) {
#pragma unroll
        for (int rg = 0; rg < 4; rg++) {
            float4 v;   // d = dt*32 + rg*8 + hi*4 + j
            v.x = o[dt][rg * 4 + 0];
            v.y = o[dt][rg * 4 + 1];
            v.z = o[dt][rg * 4 + 2];
            v.w = o[dt][rg * 4 + 3];
            *(float4*)(po + dt * 32 + rg * 8 + hi * 4) = v;
        }
    }
    if (hi == 0)
        *(float2*)(Ps + (qrow * nsplit + split) * 4 + br * 2) = float2{m, s};
}

// ---------------- split combine ----------------
__global__ __launch_bounds__(256) void combine_kernel(
    const float* __restrict__ Po, const float* __restrict__ Ps,
    const float* __restrict__ lam_p, float* __restrict__ out, int nsplit) {
    int tid = blockIdx.x * 256 + threadIdx.x;   // 16384 q * 32 threads
    int q = tid >> 5, dq = (tid & 31) * 4;
    float M1 = -1e30f, M2 = -1e30f;
    for (int s = 0; s < nsplit; s++) {
        float4 st = *(const float4*)(Ps + (long)(q * nsplit + s) * 4);
        M1 = fmaxf(M1, st.x); M2 = fmaxf(M2, st.z);
    }
    float S1 = 0.f, S2 = 0.f;
    float a0 = 0.f, a1 = 0.f, a2 = 0.f, a3 = 0.f;
    float b0 = 0.f, b1 = 0.f, b2 = 0.f, b3 = 0.f;
    for (int s = 0; s < nsplit; s++) {
        float4 st = *(const float4*)(Ps + (long)(q * nsplit + s) * 4);
        float w1 = fexp2(st.x - M1), w2 = fexp2(st.z - M2);
        S1 += st.y * w1; S2 += st.w * w2;
        const float* p1 = Po + (((long)q * nsplit + s) * 2 + 0) * 128 + dq;
        const float* p2 = Po + (((long)q * nsplit + s) * 2 + 1) * 128 + dq;
        float4 v1 = *(const float4*)p1;
        float4 v2 = *(const float4*)p2;
        a0 += v1.x * w1; a1 += v1.y * w1; a2 += v1.z * w1; a3 += v1.w * w1;
        b0 += v2.x * w2; b1 += v2.y * w2; b2 += v2.z * w2; b3 += v2.w * w2;
    }
    float lam = *lam_p;
    float i1 = 1.f / S1, i2 = lam / S2;
    float4 v;
    v.x = a0 * i1 - b0 * i2;
    v.y = a1 * i1 - b1 * i2;
    v.z = a2 * i1 - b2 * i2;
    v.w = a3 * i1 - b3 * i2;
    *(float4*)(out + (long)q * 128 + dq) = v;
}

extern "C" void kernel_launch(void* const* d_in, const int* in_sizes, int n_in,
                              void* d_out, int out_size, void* d_ws, size_t ws_size,
                              hipStream_t stream) {
    const float* X   = (const float*)d_in[0];
    const float* lam = (const float*)d_in[1];
    const float* Wq  = (const float*)d_in[2];
    const float* bq  = (const float*)d_in[3];
    const float* Wk  = (const float*)d_in[4];
    const float* bk  = (const float*)d_in[5];
    const float* Wv  = (const float*)d_in[6];
    const float* bv  = (const float*)d_in[7];
    char* ws = (char*)d_ws;
    // ws: Qs 8M | Kb 8M | Vt 4M | Wt 1.25M | @22M: Po, Ps
    unsigned short* Qs = (unsigned short*)(ws);
    unsigned short* Kb = (unsigned short*)(ws + (8u << 20));
    unsigned short* Vt = (unsigned short*)(ws + (16u << 20));
    unsigned short* Wt = (unsigned short*)(ws + (20u << 20));
    const size_t base = (size_t)22 << 20;
    // Po bytes/split = 16384q * 2br * 128 * 4B = 16 MiB; Ps = 256 KiB/split
    int nsplit = 1;
    if (ws_size >= base + 4u * (16777216u + 262144u))      nsplit = 4;
    else if (ws_size >= base + 2u * (16777216u + 262144u)) nsplit = 2;
    float* Po = (float*)(ws + base);
    float* Ps = (float*)(ws + base + (size_t)16777216 * nsplit);

    wtrans_kernel<<<2560, 256, 0, stream>>>(Wq, Wk, Wv, Wt);
    proj_kernel<<<dim3(128, 5), 256, 0, stream>>>(X, Wt, bq, bk, bv, Qs, Kb, Vt);
    attn2_kernel<<<256 * nsplit, 256, 0, stream>>>(Qs, Kb, Vt, Po, Ps,
                                                   nsplit, 4096 / nsplit);
    combine_kernel<<<2048, 256, 0, stream>>>(Po, Ps, lam, (float*)d_out, nsplit);
}

// Round 8
// 174.948 us; speedup vs baseline: 1.5271x; 1.5271x over previous
//
#include <hip/hip_runtime.h>
#include <hip/hip_bf16.h>

// DiffAttn: B=4, S=4096, EMB=1024, D=128
//   Q = X@Wq+bq (256 cols = Q1|Q2), K likewise, V = X@Wv+bv (128)
//   out = softmax(Q1K1^T/sqrt(D))@V - lam*softmax(Q2K2^T/sqrt(D))@V
// attn v5: R6 structure (512 thr, 128 q/block, grid 128*nsplit) +
//   - global_load_lds direct staging, pre-rotated global source (rule #21)
//   - 4-buffer LDS pipeline, counted s_waitcnt vmcnt(6) + raw s_barrier
//     (T3/T4: loads stay in flight across barriers; never drain to 0)
//   - in-register softmax w/ raw v_exp_f32, cvt_pk + permlane32_swap

typedef __attribute__((ext_vector_type(8))) short bf16x8;    // 8 bf16
typedef __attribute__((ext_vector_type(4))) float f32x4;
typedef __attribute__((ext_vector_type(16))) float f32x16;   // 32x32 C/D

#define MFMA16(a, b, c) __builtin_amdgcn_mfma_f32_16x16x32_bf16((a), (b), (c), 0, 0, 0)
#define MFMA32(a, b, c) __builtin_amdgcn_mfma_f32_32x32x16_bf16((a), (b), (c), 0, 0, 0)

typedef const __attribute__((address_space(1))) void gas_void;
typedef __attribute__((address_space(3))) void las_void;
#define GLOAD16(G, L) __builtin_amdgcn_global_load_lds((gas_void*)(G), (las_void*)(L), 16, 0, 0)

__device__ __forceinline__ unsigned short f2bf(float x) {
    union { float f; unsigned u; } v; v.f = x;   // RNE float->bf16
    return (unsigned short)((v.u + 0x7FFFu + ((v.u >> 16) & 1u)) >> 16);
}
__device__ __forceinline__ unsigned pk2bf(float a, float b) {   // v_cvt_pk_bf16_f32
    __hip_bfloat162 h = __float22bfloat162_rn(float2{a, b});
    union { __hip_bfloat162 h2; unsigned u; } cv; cv.h2 = h;
    return cv.u;
}
__device__ __forceinline__ float fexp2(float x) {   // raw v_exp_f32: D = 2^S0
    float r; asm("v_exp_f32 %0, %1" : "=v"(r) : "v"(x)); return r;
}

// ---------------- W transpose + bf16 convert: Wt[640][1024] ----------------
__global__ __launch_bounds__(256) void wtrans_kernel(
    const float* __restrict__ Wq, const float* __restrict__ Wk,
    const float* __restrict__ Wv, unsigned short* __restrict__ Wt) {
    int tid = blockIdx.x * 256 + threadIdx.x;   // 640*1024 total
    int k = tid & 1023, n = tid >> 10;
    float v;
    if (n < 256)      v = Wq[k * 256 + n];
    else if (n < 512) v = Wk[k * 256 + (n - 256)];
    else              v = Wv[k * 128 + (n - 512)];
    Wt[tid] = f2bf(v);
}

// ---------------- QKV projection GEMM ----------------
__global__ __launch_bounds__(256) void proj_kernel(
    const float* __restrict__ X, const unsigned short* __restrict__ Wt,
    const float* __restrict__ bq, const float* __restrict__ bk,
    const float* __restrict__ bv,
    unsigned short* __restrict__ Qs, unsigned short* __restrict__ Kb,
    unsigned short* __restrict__ Vb) {
    __shared__ alignas(16) char lds[16384];   // Xt[128][32]bf16 @0, Wtile @8192
    const int nt = blockIdx.y;
    const int m0 = blockIdx.x * 128;
    const int t = threadIdx.x, w = t >> 6, l = t & 63, c = l & 15, g = l >> 4;
    const int wm = w >> 1, wn = w & 1;
    const unsigned short* Wrow = Wt + (long)(nt * 128) * 1024;

    f32x4 acc[4][4];
    const f32x4 fz = {0.f, 0.f, 0.f, 0.f};
#pragma unroll
    for (int i = 0; i < 4; i++)
#pragma unroll
        for (int j = 0; j < 4; j++) acc[i][j] = fz;

    const int srow = t >> 1, sh = t & 1;
    const int sswz = (srow & 7) << 4;
    for (int k0 = 0; k0 < 1024; k0 += 32) {
        const float* xs = X + (long)(m0 + srow) * 1024 + k0 + sh * 16;
        float4 f0 = *(const float4*)(xs + 0);
        float4 f1 = *(const float4*)(xs + 4);
        float4 f2 = *(const float4*)(xs + 8);
        float4 f3 = *(const float4*)(xs + 12);
        const unsigned short* wsc = Wrow + (long)srow * 1024 + k0 + sh * 16;
        uint4 w0 = *(const uint4*)(wsc + 0);
        uint4 w1 = *(const uint4*)(wsc + 8);
        uint4 xa, xb;
        xa.x = pk2bf(f0.x, f0.y); xa.y = pk2bf(f0.z, f0.w);
        xa.z = pk2bf(f1.x, f1.y); xa.w = pk2bf(f1.z, f1.w);
        xb.x = pk2bf(f2.x, f2.y); xb.y = pk2bf(f2.z, f2.w);
        xb.z = pk2bf(f3.x, f3.y); xb.w = pk2bf(f3.z, f3.w);
        int base = srow * 64 + sh * 32;
        *(uint4*)(lds + ((base + 0) ^ sswz)) = xa;
        *(uint4*)(lds + ((base + 16) ^ sswz)) = xb;
        *(uint4*)(lds + 8192 + ((base + 0) ^ sswz)) = w0;
        *(uint4*)(lds + 8192 + ((base + 16) ^ sswz)) = w1;
        __syncthreads();

        bf16x8 af[4];
#pragma unroll
        for (int am = 0; am < 4; am++) {
            int r_ = wm * 64 + am * 16 + c;
            af[am] = *(const bf16x8*)(lds + ((r_ * 64 + g * 16) ^ ((c & 7) << 4)));
        }
#pragma unroll
        for (int bn = 0; bn < 4; bn++) {
            int r_ = wn * 64 + bn * 16 + c;
            bf16x8 bfr = *(const bf16x8*)(lds + 8192 + ((r_ * 64 + g * 16) ^ ((c & 7) << 4)));
#pragma unroll
            for (int am = 0; am < 4; am++) acc[am][bn] = MFMA16(af[am], bfr, acc[am][bn]);
        }
        __syncthreads();
    }

    // Q scale folds 1/sqrt(128) AND log2(e) so attn softmax is pure exp2.
    const float QSCALE = 0.08838834764831845f * 1.4426950408889634f;
    const float* bias; float scale; unsigned short* outp; int ostride, ocol0, boff;
    if (nt < 2)      { bias = bq; boff = nt * 128;       scale = QSCALE; outp = Qs; ostride = 256; ocol0 = nt * 128; }
    else if (nt < 4) { bias = bk; boff = (nt - 2) * 128; scale = 1.0f;   outp = Kb; ostride = 256; ocol0 = (nt - 2) * 128; }
    else             { bias = bv; boff = 0;              scale = 1.0f;   outp = Vb; ostride = 128; ocol0 = 0; }
#pragma unroll
    for (int bn = 0; bn < 4; bn++) {
        int ncol = wn * 64 + bn * 16 + c;
        float bb = bias[boff + ncol];
#pragma unroll
        for (int am = 0; am < 4; am++) {
#pragma unroll
            for (int r = 0; r < 4; r++) {
                long row = m0 + wm * 64 + am * 16 + 4 * g + r;
                outp[row * ostride + ocol0 + ncol] = f2bf((acc[am][bn][r] + bb) * scale);
            }
        }
    }
}

// ---------------- V transpose: Vt[b][128][4096] ----------------
__global__ __launch_bounds__(256) void vtrans_kernel(
    const unsigned short* __restrict__ Vb, unsigned short* __restrict__ Vt) {
    int tid = blockIdx.x * 256 + threadIdx.x;   // 4*128*4096
    int s = tid & 4095, d = (tid >> 12) & 127, b = tid >> 19;
    Vt[tid] = Vb[(((long)b << 12) + s) * 128 + d];
}

// ---------------- flash diff-attention v5 ----------------
// 512 threads = 8 waves = 4 q-sub x 2 branches, 128 q/block.
// LDS: 4 buffers x 24KB {K1[32][256] rot | K2 | V[128][64] rot}.
// Staging: global_load_lds w/ pre-rotated per-lane SOURCE, linear dest.
//   K LDS col = (orig + row*16) & 255 ; V LDS col = (orig + ((d>>1)&3)*16) & 63
// Pipeline: 3 tiles in flight; per iter ONE vmcnt(6) + ONE raw s_barrier.
__global__ __launch_bounds__(512) void attn3_kernel(
    const unsigned short* __restrict__ Qs, const unsigned short* __restrict__ Kb,
    const unsigned short* __restrict__ Vt,
    float* __restrict__ Po, float* __restrict__ Ps, int nsplit, int ks) {
    __shared__ alignas(16) char lds[98304];
    const int t = threadIdx.x;
    const int w = t >> 6, l = t & 63, r31 = l & 31, hi = l >> 5;
    const int wq = w >> 1, br = w & 1;

    const int total = gridDim.x;
    const int lin = (blockIdx.x & 7) * (total >> 3) + (blockIdx.x >> 3);
    const int grp = lin >> 5, qb = lin & 31;
    const int b = grp / nsplit, split = grp % nsplit;

    const long qrow = (long)b * 4096 + qb * 128 + wq * 32 + r31;
    bf16x8 qf[8];
    const unsigned short* Qp = Qs + qrow * 256 + br * 128 + hi * 8;
#pragma unroll
    for (int ds = 0; ds < 8; ds++) qf[ds] = *(const bf16x8*)(Qp + ds * 16);

    f32x16 o[4];
    const f32x16 oz = {};
#pragma unroll
    for (int dt = 0; dt < 4; dt++) o[dt] = oz;
    float m = -1e30f, s = 0.f;

    // --- staging geometry: wave-linear LDS dest, rotated global source ---
    const int krow = w * 4 + (l >> 4);            // K row 0..31
    const int kc = (l & 15) * 16;                 // K LDS col byte
    const int ksrc_rot = (kc - krow * 16) & 255;  // source col within 512B row
    const int vd = w * 16 + (l >> 2);             // V row (d) 0..127
    const int vc = (l & 3) * 16;
    const long kbb = (long)b * 4096;
    const char* KbB = (const char*)Kb;
    const char* VtB = (const char*)Vt + ((long)b * 128 + vd) * 8192 +
                      ((vc - ((vd >> 1) & 3) * 16) & 63);
    char* dst0 = lds + w * 1024;                  // wave-uniform

    const int kb0 = split * ks, kend = kb0 + ks;
#define STAGE(KB_, BUF_)                                                       \
    {                                                                          \
        const char* s1_ = KbB + (kbb + (KB_) + krow) * 512 + ksrc_rot;         \
        char* d_ = dst0 + (BUF_)*24576;                                        \
        GLOAD16(s1_, d_);                                                      \
        GLOAD16(s1_ + 256, d_ + 8192);                                         \
        GLOAD16(VtB + (long)(KB_)*2, d_ + 16384);                              \
    }

    // --- read offsets (loop-invariant) ---
    int kro[8];
#pragma unroll
    for (int ds = 0; ds < 8; ds++)
        kro[ds] = br * 8192 + r31 * 256 + ((ds * 32 + hi * 16 + r31 * 16) & 255);
    int vro0[4], vro1[4];
#pragma unroll
    for (int dt = 0; dt < 4; dt++) {
        int vr = dt * 32 + r31, rot = ((vr >> 1) & 3) * 16;
        vro0[dt] = 16384 + vr * 64 + ((hi * 16 + rot) & 63);
        vro1[dt] = 16384 + vr * 64 + ((32 + hi * 16 + rot) & 63);
    }

    // prologue: 3 tiles in flight (ks >= 1024 so kb0+64 < kend always)
    STAGE(kb0, 0);
    STAGE(kb0 + 32, 1);
    STAGE(kb0 + 64, 2);
    int cur = 0;

    for (int kb = kb0; kb < kend; kb += 32) {
        // tile kb ready when my 3 oldest staging loads retire (Q loads are
        // older still and retire first). Keep 6 (= 2 tiles) in flight.
        asm volatile("s_waitcnt vmcnt(6)" ::: "memory");
        __builtin_amdgcn_sched_barrier(0);
        __builtin_amdgcn_s_barrier();
        asm volatile("" ::: "memory");
        __builtin_amdgcn_sched_barrier(0);

        // issue tile kb+96 into buf[(cur+3)&3] (= buf of tile kb-1: all waves
        // passed this iter's barrier => all finished computing kb-1). Dummy
        // reload of kb0 in the tail keeps vmcnt arithmetic uniform.
        {
            int kn = kb + 96;
            if (kn >= kend) kn = kb0;
            STAGE(kn, (cur + 3) & 3);
        }
        const char* bufp = lds + cur * 24576;

        // ---- QK^T: P^T[key][q], two independent 4-deep chains ----
        f32x16 pa = oz, pb_ = oz;
        __builtin_amdgcn_s_setprio(1);
#pragma unroll
        for (int ds = 0; ds < 4; ds++) {
            bf16x8 kfa = *(const bf16x8*)(bufp + kro[ds]);
            bf16x8 kfb = *(const bf16x8*)(bufp + kro[ds + 4]);
            pa = MFMA32(kfa, qf[ds], pa);
            pb_ = MFMA32(kfb, qf[ds + 4], pb_);
        }
        __builtin_amdgcn_s_setprio(0);
        f32x16 p;
#pragma unroll
        for (int i = 0; i < 16; i++) p[i] = pa[i] + pb_[i];

        // ---- in-register softmax (exp2 domain; defer-max THR=8) ----
        float x0 = fmaxf(fmaxf(p[0], p[1]), fmaxf(p[2], p[3]));
        float x1 = fmaxf(fmaxf(p[4], p[5]), fmaxf(p[6], p[7]));
        float x2 = fmaxf(fmaxf(p[8], p[9]), fmaxf(p[10], p[11]));
        float x3 = fmaxf(fmaxf(p[12], p[13]), fmaxf(p[14], p[15]));
        float lmx = fmaxf(fmaxf(x0, x1), fmaxf(x2, x3));
        lmx = fmaxf(lmx, __shfl_xor(lmx, 32));
        if (__any(lmx > m + 8.f)) {
            float mn = fmaxf(m, lmx);
            float al = fexp2(m - mn);
            s *= al; m = mn;
#pragma unroll
            for (int dt = 0; dt < 4; dt++) o[dt] *= al;
        }
        float pe[16];
#pragma unroll
        for (int i = 0; i < 16; i++) pe[i] = fexp2(p[i] - m);
        float s0 = (pe[0] + pe[1]) + (pe[2] + pe[3]);
        float s1 = (pe[4] + pe[5]) + (pe[6] + pe[7]);
        float s2 = (pe[8] + pe[9]) + (pe[10] + pe[11]);
        float s3 = (pe[12] + pe[13]) + (pe[14] + pe[15]);
        float ps_ = (s0 + s1) + (s2 + s3);
        ps_ += __shfl_xor(ps_, 32);
        s += ps_;

        // ---- P -> PV B-fragments (cvt_pk + permlane32_swap) ----
        unsigned cA = pk2bf(pe[0], pe[1]), cB = pk2bf(pe[2], pe[3]);
        unsigned cC = pk2bf(pe[4], pe[5]), cD = pk2bf(pe[6], pe[7]);
        asm volatile("v_permlane32_swap_b32 %0, %1" : "+v"(cA), "+v"(cC));
        asm volatile("v_permlane32_swap_b32 %0, %1" : "+v"(cB), "+v"(cD));
        unsigned dA = pk2bf(pe[8], pe[9]), dB = pk2bf(pe[10], pe[11]);
        unsigned dC = pk2bf(pe[12], pe[13]), dD = pk2bf(pe[14], pe[15]);
        asm volatile("v_permlane32_swap_b32 %0, %1" : "+v"(dA), "+v"(dC));
        asm volatile("v_permlane32_swap_b32 %0, %1" : "+v"(dB), "+v"(dD));
        union { uint4 u; bf16x8 v; } pb0, pb1;
        pb0.u = uint4{cA, cB, cC, cD};   // keys 0-15
        pb1.u = uint4{dA, dB, dC, dD};   // keys 16-31

        // ---- PV: O^T[d][q] += V^T-frag x PB ----
        __builtin_amdgcn_s_setprio(1);
#pragma unroll
        for (int dt = 0; dt < 4; dt++) {
            bf16x8 vf0 = *(const bf16x8*)(bufp + vro0[dt]);
            bf16x8 vf1 = *(const bf16x8*)(bufp + vro1[dt]);
            o[dt] = MFMA32(vf0, pb0.v, o[dt]);
            o[dt] = MFMA32(vf1, pb1.v, o[dt]);
        }
        __builtin_amdgcn_s_setprio(0);
        cur = (cur + 1) & 3;
    }

    // ---- epilogue: per-branch partials ----
    float* po = Po + ((qrow * nsplit + split) * 2 + br) * 128;
#pragma unroll
    for (int dt = 0; dt < 4; dt++) {
#pragma unroll
        for (int rg = 0; rg < 4; rg++) {
            float4 v;   // d = dt*32 + rg*8 + hi*4 + j
            v.x = o[dt][rg * 4 + 0];
            v.y = o[dt][rg * 4 + 1];
            v.z = o[dt][rg * 4 + 2];
            v.w = o[dt][rg * 4 + 3];
            *(float4*)(po + dt * 32 + rg * 8 + hi * 4) = v;
        }
    }
    if (hi == 0)
        *(float2*)(Ps + (qrow * nsplit + split) * 4 + br * 2) = float2{m, s};
}

// ---------------- split combine ----------------
__global__ __launch_bounds__(256) void combine_kernel(
    const float* __restrict__ Po, const float* __restrict__ Ps,
    const float* __restrict__ lam_p, float* __restrict__ out, int nsplit) {
    int tid = blockIdx.x * 256 + threadIdx.x;   // 16384 q * 32 threads
    int q = tid >> 5, dq = (tid & 31) * 4;
    float M1 = -1e30f, M2 = -1e30f;
    for (int s = 0; s < nsplit; s++) {
        float4 st = *(const float4*)(Ps + (long)(q * nsplit + s) * 4);
        M1 = fmaxf(M1, st.x); M2 = fmaxf(M2, st.z);
    }
    float S1 = 0.f, S2 = 0.f;
    float a0 = 0.f, a1 = 0.f, a2 = 0.f, a3 = 0.f;
    float b0 = 0.f, b1 = 0.f, b2 = 0.f, b3 = 0.f;
    for (int s = 0; s < nsplit; s++) {
        float4 st = *(const float4*)(Ps + (long)(q * nsplit + s) * 4);
        float w1 = fexp2(st.x - M1), w2 = fexp2(st.z - M2);
        S1 += st.y * w1; S2 += st.w * w2;
        const float* p1 = Po + (((long)q * nsplit + s) * 2 + 0) * 128 + dq;
        const float* p2 = Po + (((long)q * nsplit + s) * 2 + 1) * 128 + dq;
        float4 v1 = *(const float4*)p1;
        float4 v2 = *(const float4*)p2;
        a0 += v1.x * w1; a1 += v1.y * w1; a2 += v1.z * w1; a3 += v1.w * w1;
        b0 += v2.x * w2; b1 += v2.y * w2; b2 += v2.z * w2; b3 += v2.w * w2;
    }
    float lam = *lam_p;
    float i1 = 1.f / S1, i2 = lam / S2;
    float4 v;
    v.x = a0 * i1 - b0 * i2;
    v.y = a1 * i1 - b1 * i2;
    v.z = a2 * i1 - b2 * i2;
    v.w = a3 * i1 - b3 * i2;
    *(float4*)(out + (long)q * 128 + dq) = v;
}

extern "C" void kernel_launch(void* const* d_in, const int* in_sizes, int n_in,
                              void* d_out, int out_size, void* d_ws, size_t ws_size,
                              hipStream_t stream) {
    const float* X   = (const float*)d_in[0];
    const float* lam = (const float*)d_in[1];
    const float* Wq  = (const float*)d_in[2];
    const float* bq  = (const float*)d_in[3];
    const float* Wk  = (const float*)d_in[4];
    const float* bk  = (const float*)d_in[5];
    const float* Wv  = (const float*)d_in[6];
    const float* bv  = (const float*)d_in[7];
    char* ws = (char*)d_ws;
    // ws: Qs 8M | Kb 8M | Vb 4M | Vt 4M | Wt 1.25M | @26M: Po, Ps
    unsigned short* Qs = (unsigned short*)(ws);
    unsigned short* Kb = (unsigned short*)(ws + (8u << 20));
    unsigned short* Vb = (unsigned short*)(ws + (16u << 20));
    unsigned short* Vt = (unsigned short*)(ws + (20u << 20));
    unsigned short* Wt = (unsigned short*)(ws + (24u << 20));
    const size_t base = (size_t)26 << 20;
    const size_t NQ = 16384;
    int nsplit = 1;
    if (ws_size >= base + NQ * 4 * 2 * 128 * 4 + NQ * 4 * 4 * 4)      nsplit = 4;
    else if (ws_size >= base + NQ * 2 * 2 * 128 * 4 + NQ * 2 * 4 * 4) nsplit = 2;
    float* Po = (float*)(ws + base);
    float* Ps = (float*)(ws + base + NQ * (size_t)nsplit * 2 * 128 * 4);

    wtrans_kernel<<<2560, 256, 0, stream>>>(Wq, Wk, Wv, Wt);
    proj_kernel<<<dim3(128, 5), 256, 0, stream>>>(X, Wt, bq, bk, bv, Qs, Kb, Vb);
    vtrans_kernel<<<8192, 256, 0, stream>>>(Vb, Vt);
    attn3_kernel<<<128 * nsplit, 512, 0, stream>>>(Qs, Kb, Vt, Po, Ps,
                                                   nsplit, 4096 / nsplit);
    combine_kernel<<<2048, 256, 0, stream>>>(Po, Ps, lam, (float*)d_out, nsplit);
}

// Round 9
// 170.989 us; speedup vs baseline: 1.5624x; 1.0232x over previous
//
#include <hip/hip_runtime.h>
#include <hip/hip_bf16.h>

// DiffAttn: B=4, S=4096, EMB=1024, D=128
//   Q = X@Wq+bq (256 cols = Q1|Q2), K likewise, V = X@Wv+bv (128)
//   out = softmax(Q1K1^T/sqrt(D))@V - lam*softmax(Q2K2^T/sqrt(D))@V
// attn v6 = v5 + T15 QK-ahead pipeline: QK^T(tile i+1) issues before
// softmax/PV(tile i), hiding the serial QK->softmax->PV chain under the
// other branch of the pipeline. Two named P states (pA/pB), 2x-unrolled.

typedef __attribute__((ext_vector_type(8))) short bf16x8;    // 8 bf16
typedef __attribute__((ext_vector_type(4))) float f32x4;
typedef __attribute__((ext_vector_type(16))) float f32x16;   // 32x32 C/D

#define MFMA16(a, b, c) __builtin_amdgcn_mfma_f32_16x16x32_bf16((a), (b), (c), 0, 0, 0)
#define MFMA32(a, b, c) __builtin_amdgcn_mfma_f32_32x32x16_bf16((a), (b), (c), 0, 0, 0)

typedef const __attribute__((address_space(1))) void gas_void;
typedef __attribute__((address_space(3))) void las_void;
#define GLOAD16(G, L) __builtin_amdgcn_global_load_lds((gas_void*)(G), (las_void*)(L), 16, 0, 0)

__device__ __forceinline__ unsigned short f2bf(float x) {
    union { float f; unsigned u; } v; v.f = x;   // RNE float->bf16
    return (unsigned short)((v.u + 0x7FFFu + ((v.u >> 16) & 1u)) >> 16);
}
__device__ __forceinline__ unsigned pk2bf(float a, float b) {   // v_cvt_pk_bf16_f32
    __hip_bfloat162 h = __float22bfloat162_rn(float2{a, b});
    union { __hip_bfloat162 h2; unsigned u; } cv; cv.h2 = h;
    return cv.u;
}
__device__ __forceinline__ float fexp2(float x) {   // raw v_exp_f32: D = 2^S0
    float r; asm("v_exp_f32 %0, %1" : "=v"(r) : "v"(x)); return r;
}

// ---------------- W transpose + bf16 convert: Wt[640][1024] ----------------
__global__ __launch_bounds__(256) void wtrans_kernel(
    const float* __restrict__ Wq, const float* __restrict__ Wk,
    const float* __restrict__ Wv, unsigned short* __restrict__ Wt) {
    int tid = blockIdx.x * 256 + threadIdx.x;   // 640*1024 total
    int k = tid & 1023, n = tid >> 10;
    float v;
    if (n < 256)      v = Wq[k * 256 + n];
    else if (n < 512) v = Wk[k * 256 + (n - 256)];
    else              v = Wv[k * 128 + (n - 512)];
    Wt[tid] = f2bf(v);
}

// ---------------- QKV projection GEMM ----------------
__global__ __launch_bounds__(256) void proj_kernel(
    const float* __restrict__ X, const unsigned short* __restrict__ Wt,
    const float* __restrict__ bq, const float* __restrict__ bk,
    const float* __restrict__ bv,
    unsigned short* __restrict__ Qs, unsigned short* __restrict__ Kb,
    unsigned short* __restrict__ Vb) {
    __shared__ alignas(16) char lds[16384];   // Xt[128][32]bf16 @0, Wtile @8192
    const int nt = blockIdx.y;
    const int m0 = blockIdx.x * 128;
    const int t = threadIdx.x, w = t >> 6, l = t & 63, c = l & 15, g = l >> 4;
    const int wm = w >> 1, wn = w & 1;
    const unsigned short* Wrow = Wt + (long)(nt * 128) * 1024;

    f32x4 acc[4][4];
    const f32x4 fz = {0.f, 0.f, 0.f, 0.f};
#pragma unroll
    for (int i = 0; i < 4; i++)
#pragma unroll
        for (int j = 0; j < 4; j++) acc[i][j] = fz;

    const int srow = t >> 1, sh = t & 1;
    const int sswz = (srow & 7) << 4;
    for (int k0 = 0; k0 < 1024; k0 += 32) {
        const float* xs = X + (long)(m0 + srow) * 1024 + k0 + sh * 16;
        float4 f0 = *(const float4*)(xs + 0);
        float4 f1 = *(const float4*)(xs + 4);
        float4 f2 = *(const float4*)(xs + 8);
        float4 f3 = *(const float4*)(xs + 12);
        const unsigned short* wsc = Wrow + (long)srow * 1024 + k0 + sh * 16;
        uint4 w0 = *(const uint4*)(wsc + 0);
        uint4 w1 = *(const uint4*)(wsc + 8);
        uint4 xa, xb;
        xa.x = pk2bf(f0.x, f0.y); xa.y = pk2bf(f0.z, f0.w);
        xa.z = pk2bf(f1.x, f1.y); xa.w = pk2bf(f1.z, f1.w);
        xb.x = pk2bf(f2.x, f2.y); xb.y = pk2bf(f2.z, f2.w);
        xb.z = pk2bf(f3.x, f3.y); xb.w = pk2bf(f3.z, f3.w);
        int base = srow * 64 + sh * 32;
        *(uint4*)(lds + ((base + 0) ^ sswz)) = xa;
        *(uint4*)(lds + ((base + 16) ^ sswz)) = xb;
        *(uint4*)(lds + 8192 + ((base + 0) ^ sswz)) = w0;
        *(uint4*)(lds + 8192 + ((base + 16) ^ sswz)) = w1;
        __syncthreads();

        bf16x8 af[4];
#pragma unroll
        for (int am = 0; am < 4; am++) {
            int r_ = wm * 64 + am * 16 + c;
            af[am] = *(const bf16x8*)(lds + ((r_ * 64 + g * 16) ^ ((c & 7) << 4)));
        }
#pragma unroll
        for (int bn = 0; bn < 4; bn++) {
            int r_ = wn * 64 + bn * 16 + c;
            bf16x8 bfr = *(const bf16x8*)(lds + 8192 + ((r_ * 64 + g * 16) ^ ((c & 7) << 4)));
#pragma unroll
            for (int am = 0; am < 4; am++) acc[am][bn] = MFMA16(af[am], bfr, acc[am][bn]);
        }
        __syncthreads();
    }

    // Q scale folds 1/sqrt(128) AND log2(e) so attn softmax is pure exp2.
    const float QSCALE = 0.08838834764831845f * 1.4426950408889634f;
    const float* bias; float scale; unsigned short* outp; int ostride, ocol0, boff;
    if (nt < 2)      { bias = bq; boff = nt * 128;       scale = QSCALE; outp = Qs; ostride = 256; ocol0 = nt * 128; }
    else if (nt < 4) { bias = bk; boff = (nt - 2) * 128; scale = 1.0f;   outp = Kb; ostride = 256; ocol0 = (nt - 2) * 128; }
    else             { bias = bv; boff = 0;              scale = 1.0f;   outp = Vb; ostride = 128; ocol0 = 0; }
#pragma unroll
    for (int bn = 0; bn < 4; bn++) {
        int ncol = wn * 64 + bn * 16 + c;
        float bb = bias[boff + ncol];
#pragma unroll
        for (int am = 0; am < 4; am++) {
#pragma unroll
            for (int r = 0; r < 4; r++) {
                long row = m0 + wm * 64 + am * 16 + 4 * g + r;
                outp[row * ostride + ocol0 + ncol] = f2bf((acc[am][bn][r] + bb) * scale);
            }
        }
    }
}

// ---------------- V transpose: Vt[b][128][4096] ----------------
__global__ __launch_bounds__(256) void vtrans_kernel(
    const unsigned short* __restrict__ Vb, unsigned short* __restrict__ Vt) {
    int tid = blockIdx.x * 256 + threadIdx.x;   // 4*128*4096
    int s = tid & 4095, d = (tid >> 12) & 127, b = tid >> 19;
    Vt[tid] = Vb[(((long)b << 12) + s) * 128 + d];
}

// ---------------- flash diff-attention v6 (T15 QK-ahead) ----------------
// 512 threads = 8 waves = 4 q-sub x 2 branches, 128 q/block.
// LDS: 4 buffers x 24KB {K1[32][256] rot | K2 | V[128][64] rot}.
// Per step i: vmcnt(3)+barrier (tiles i,i+1 resident); STAGE(i+3);
// QK(i+1)->pNext (overlaps softmax); softmax(pCur)+PV(i).
__global__ __launch_bounds__(512) void attn3_kernel(
    const unsigned short* __restrict__ Qs, const unsigned short* __restrict__ Kb,
    const unsigned short* __restrict__ Vt,
    float* __restrict__ Po, float* __restrict__ Ps, int nsplit, int ks) {
    __shared__ alignas(16) char lds[98304];
    const int t = threadIdx.x;
    const int w = t >> 6, l = t & 63, r31 = l & 31, hi = l >> 5;
    const int wq = w >> 1, br = w & 1;

    const int total = gridDim.x;
    const int lin = (blockIdx.x & 7) * (total >> 3) + (blockIdx.x >> 3);
    const int grp = lin >> 5, qb = lin & 31;
    const int b = grp / nsplit, split = grp % nsplit;

    const long qrow = (long)b * 4096 + qb * 128 + wq * 32 + r31;
    bf16x8 qf[8];
    const unsigned short* Qp = Qs + qrow * 256 + br * 128 + hi * 8;
#pragma unroll
    for (int ds = 0; ds < 8; ds++) qf[ds] = *(const bf16x8*)(Qp + ds * 16);

    f32x16 o[4];
    const f32x16 oz = {};
#pragma unroll
    for (int dt = 0; dt < 4; dt++) o[dt] = oz;
    float m = -1e30f, s = 0.f;

    // --- staging geometry: wave-linear LDS dest, rotated global source ---
    const int krow = w * 4 + (l >> 4);            // K row 0..31
    const int kc = (l & 15) * 16;                 // K LDS col byte
    const int ksrc_rot = (kc - krow * 16) & 255;  // source col within 512B row
    const int vd = w * 16 + (l >> 2);             // V row (d) 0..127
    const int vc = (l & 3) * 16;
    const long kbb = (long)b * 4096;
    const char* KbB = (const char*)Kb;
    const char* VtB = (const char*)Vt + ((long)b * 128 + vd) * 8192 +
                      ((vc - ((vd >> 1) & 3) * 16) & 63);
    char* dst0 = lds + w * 1024;                  // wave-uniform

    const int kb0 = split * ks, kend = kb0 + ks;
    const int nt = ks >> 5;                       // tiles (even, >= 32)
#define STAGE(KB_, BUF_)                                                       \
    {                                                                          \
        const char* s1_ = KbB + (kbb + (KB_) + krow) * 512 + ksrc_rot;         \
        char* d_ = dst0 + (BUF_)*24576;                                        \
        GLOAD16(s1_, d_);                                                      \
        GLOAD16(s1_ + 256, d_ + 8192);                                         \
        GLOAD16(VtB + (long)(KB_)*2, d_ + 16384);                              \
    }

    // --- read offsets (loop-invariant) ---
    int kro[8];
#pragma unroll
    for (int ds = 0; ds < 8; ds++)
        kro[ds] = br * 8192 + r31 * 256 + ((ds * 32 + hi * 16 + r31 * 16) & 255);
    int vro0[4], vro1[4];
#pragma unroll
    for (int dt = 0; dt < 4; dt++) {
        int vr = dt * 32 + r31, rot = ((vr >> 1) & 3) * 16;
        vro0[dt] = 16384 + vr * 64 + ((hi * 16 + rot) & 63);
        vro1[dt] = 16384 + vr * 64 + ((32 + hi * 16 + rot) & 63);
    }

#define FENCE_TOP(N)                                                           \
    asm volatile("s_waitcnt vmcnt(" #N ")" ::: "memory");                      \
    __builtin_amdgcn_sched_barrier(0);                                         \
    __builtin_amdgcn_s_barrier();                                              \
    __builtin_amdgcn_sched_barrier(0);

    // QK^T of tile TI -> PN (reads buf[TI&3]; 2 independent 4-deep chains)
#define QKTILE(PN, TI)                                                         \
    {                                                                          \
        const char* kp_ = lds + ((TI) & 3) * 24576;                            \
        f32x16 qa_ = oz, qb_ = oz;                                             \
        _Pragma("unroll") for (int d_ = 0; d_ < 4; d_++) {                     \
            bf16x8 ka_ = *(const bf16x8*)(kp_ + kro[d_]);                      \
            bf16x8 kb_ = *(const bf16x8*)(kp_ + kro[d_ + 4]);                  \
            qa_ = MFMA32(ka_, qf[d_], qa_);                                    \
            qb_ = MFMA32(kb_, qf[d_ + 4], qb_);                                \
        }                                                                      \
        _Pragma("unroll") for (int i_ = 0; i_ < 16; i_++)                      \
            PN[i_] = qa_[i_] + qb_[i_];                                        \
    }

    // softmax(PC) + PV from buf[TI&3]
#define SOFTPV(PC, TI)                                                         \
    {                                                                          \
        float x0 = fmaxf(fmaxf(PC[0], PC[1]), fmaxf(PC[2], PC[3]));            \
        float x1 = fmaxf(fmaxf(PC[4], PC[5]), fmaxf(PC[6], PC[7]));            \
        float x2 = fmaxf(fmaxf(PC[8], PC[9]), fmaxf(PC[10], PC[11]));          \
        float x3 = fmaxf(fmaxf(PC[12], PC[13]), fmaxf(PC[14], PC[15]));        \
        float lmx = fmaxf(fmaxf(x0, x1), fmaxf(x2, x3));                       \
        lmx = fmaxf(lmx, __shfl_xor(lmx, 32));                                 \
        if (__any(lmx > m + 8.f)) {                                            \
            float mn = fmaxf(m, lmx);                                          \
            float al = fexp2(m - mn);                                          \
            s *= al; m = mn;                                                   \
            _Pragma("unroll") for (int dt_ = 0; dt_ < 4; dt_++) o[dt_] *= al;  \
        }                                                                      \
        float pe[16];                                                          \
        _Pragma("unroll") for (int i_ = 0; i_ < 16; i_++)                      \
            pe[i_] = fexp2(PC[i_] - m);                                        \
        float s0 = (pe[0] + pe[1]) + (pe[2] + pe[3]);                          \
        float s1 = (pe[4] + pe[5]) + (pe[6] + pe[7]);                          \
        float s2 = (pe[8] + pe[9]) + (pe[10] + pe[11]);                        \
        float s3 = (pe[12] + pe[13]) + (pe[14] + pe[15]);                      \
        float ps_ = (s0 + s1) + (s2 + s3);                                     \
        ps_ += __shfl_xor(ps_, 32);                                            \
        s += ps_;                                                              \
        unsigned cA = pk2bf(pe[0], pe[1]), cB = pk2bf(pe[2], pe[3]);           \
        unsigned cC = pk2bf(pe[4], pe[5]), cD = pk2bf(pe[6], pe[7]);           \
        asm volatile("v_permlane32_swap_b32 %0, %1" : "+v"(cA), "+v"(cC));     \
        asm volatile("v_permlane32_swap_b32 %0, %1" : "+v"(cB), "+v"(cD));     \
        unsigned dA = pk2bf(pe[8], pe[9]), dB = pk2bf(pe[10], pe[11]);         \
        unsigned dC = pk2bf(pe[12], pe[13]), dD = pk2bf(pe[14], pe[15]);       \
        asm volatile("v_permlane32_swap_b32 %0, %1" : "+v"(dA), "+v"(dC));     \
        asm volatile("v_permlane32_swap_b32 %0, %1" : "+v"(dB), "+v"(dD));     \
        union { uint4 u; bf16x8 v; } pb0_, pb1_;                               \
        pb0_.u = uint4{cA, cB, cC, cD};                                        \
        pb1_.u = uint4{dA, dB, dC, dD};                                        \
        const char* vb_ = lds + ((TI) & 3) * 24576;                            \
        _Pragma("unroll") for (int dt_ = 0; dt_ < 4; dt_++) {                  \
            bf16x8 vf0 = *(const bf16x8*)(vb_ + vro0[dt_]);                    \
            bf16x8 vf1 = *(const bf16x8*)(vb_ + vro1[dt_]);                    \
            o[dt_] = MFMA32(vf0, pb0_.v, o[dt_]);                              \
            o[dt_] = MFMA32(vf1, pb1_.v, o[dt_]);                              \
        }                                                                      \
    }

    // step i: fences; stage i+3; QK(i+1)->PN; softmax(PC)+PV(i)
#define STEP(PC, PN, I)                                                        \
    {                                                                          \
        FENCE_TOP(3)                                                           \
        {                                                                      \
            int i3_ = (I) + 3;                                                 \
            int kn_ = (i3_ < nt) ? kb0 + (i3_ << 5) : kb0;                     \
            STAGE(kn_, i3_ & 3);                                               \
        }                                                                      \
        QKTILE(PN, (I) + 1)                                                    \
        SOFTPV(PC, (I))                                                        \
    }

    // prologue: 3 tiles in flight; QK(tile 0) ahead
    STAGE(kb0, 0);
    STAGE(kb0 + 32, 1);
    STAGE(kb0 + 64, 2);
    f32x16 pA, pB;
    FENCE_TOP(6)
    QKTILE(pA, 0)

    int it = 0;
    for (; it + 2 < nt; it += 2) {
        STEP(pA, pB, it)
        STEP(pB, pA, it + 1)
    }
    STEP(pA, pB, nt - 2)
    FENCE_TOP(3)
    SOFTPV(pB, nt - 1)
    asm volatile("s_waitcnt vmcnt(0)" ::: "memory");

    // ---- epilogue: per-branch partials ----
    float* po = Po + ((qrow * nsplit + split) * 2 + br) * 128;
#pragma unroll
    for (int dt = 0; dt < 4; dt++) {
#pragma unroll
        for (int rg = 0; rg < 4; rg++) {
            float4 v;   // d = dt*32 + rg*8 + hi*4 + j
            v.x = o[dt][rg * 4 + 0];
            v.y = o[dt][rg * 4 + 1];
            v.z = o[dt][rg * 4 + 2];
            v.w = o[dt][rg * 4 + 3];
            *(float4*)(po + dt * 32 + rg * 8 + hi * 4) = v;
        }
    }
    if (hi == 0)
        *(float2*)(Ps + (qrow * nsplit + split) * 4 + br * 2) = float2{m, s};
#undef STAGE
#undef FENCE_TOP
#undef QKTILE
#undef SOFTPV
#undef STEP
}

// ---------------- split combine ----------------
__global__ __launch_bounds__(256) void combine_kernel(
    const float* __restrict__ Po, const float* __restrict__ Ps,
    const float* __restrict__ lam_p, float* __restrict__ out, int nsplit) {
    int tid = blockIdx.x * 256 + threadIdx.x;   // 16384 q * 32 threads
    int q = tid >> 5, dq = (tid & 31) * 4;
    float M1 = -1e30f, M2 = -1e30f;
    for (int s = 0; s < nsplit; s++) {
        float4 st = *(const float4*)(Ps + (long)(q * nsplit + s) * 4);
        M1 = fmaxf(M1, st.x); M2 = fmaxf(M2, st.z);
    }
    float S1 = 0.f, S2 = 0.f;
    float a0 = 0.f, a1 = 0.f, a2 = 0.f, a3 = 0.f;
    float b0 = 0.f, b1 = 0.f, b2 = 0.f, b3 = 0.f;
    for (int s = 0; s < nsplit; s++) {
        float4 st = *(const float4*)(Ps + (long)(q * nsplit + s) * 4);
        float w1 = fexp2(st.x - M1), w2 = fexp2(st.z - M2);
        S1 += st.y * w1; S2 += st.w * w2;
        const float* p1 = Po + (((long)q * nsplit + s) * 2 + 0) * 128 + dq;
        const float* p2 = Po + (((long)q * nsplit + s) * 2 + 1) * 128 + dq;
        float4 v1 = *(const float4*)p1;
        float4 v2 = *(const float4*)p2;
        a0 += v1.x * w1; a1 += v1.y * w1; a2 += v1.z * w1; a3 += v1.w * w1;
        b0 += v2.x * w2; b1 += v2.y * w2; b2 += v2.z * w2; b3 += v2.w * w2;
    }
    float lam = *lam_p;
    float i1 = 1.f / S1, i2 = lam / S2;
    float4 v;
    v.x = a0 * i1 - b0 * i2;
    v.y = a1 * i1 - b1 * i2;
    v.z = a2 * i1 - b2 * i2;
    v.w = a3 * i1 - b3 * i2;
    *(float4*)(out + (long)q * 128 + dq) = v;
}

extern "C" void kernel_launch(void* const* d_in, const int* in_sizes, int n_in,
                              void* d_out, int out_size, void* d_ws, size_t ws_size,
                              hipStream_t stream) {
    const float* X   = (const float*)d_in[0];
    const float* lam = (const float*)d_in[1];
    const float* Wq  = (const float*)d_in[2];
    const float* bq  = (const float*)d_in[3];
    const float* Wk  = (const float*)d_in[4];
    const float* bk  = (const float*)d_in[5];
    const float* Wv  = (const float*)d_in[6];
    const float* bv  = (const float*)d_in[7];
    char* ws = (char*)d_ws;
    // ws: Qs 8M | Kb 8M | Vb 4M | Vt 4M | Wt 1.25M | @26M: Po, Ps
    unsigned short* Qs = (unsigned short*)(ws);
    unsigned short* Kb = (unsigned short*)(ws + (8u << 20));
    unsigned short* Vb = (unsigned short*)(ws + (16u << 20));
    unsigned short* Vt = (unsigned short*)(ws + (20u << 20));
    unsigned short* Wt = (unsigned short*)(ws + (24u << 20));
    const size_t base = (size_t)26 << 20;
    const size_t NQ = 16384;
    int nsplit = 1;
    if (ws_size >= base + NQ * 4 * 2 * 128 * 4 + NQ * 4 * 4 * 4)      nsplit = 4;
    else if (ws_size >= base + NQ * 2 * 2 * 128 * 4 + NQ * 2 * 4 * 4) nsplit = 2;
    float* Po = (float*)(ws + base);
    float* Ps = (float*)(ws + base + NQ * (size_t)nsplit * 2 * 128 * 4);

    wtrans_kernel<<<2560, 256, 0, stream>>>(Wq, Wk, Wv, Wt);
    proj_kernel<<<dim3(128, 5), 256, 0, stream>>>(X, Wt, bq, bk, bv, Qs, Kb, Vb);
    vtrans_kernel<<<8192, 256, 0, stream>>>(Vb, Vt);
    attn3_kernel<<<128 * nsplit, 512, 0, stream>>>(Qs, Kb, Vt, Po, Ps,
                                                   nsplit, 4096 / nsplit);
    combine_kernel<<<2048, 256, 0, stream>>>(Po, Ps, lam, (float*)d_out, nsplit);
}

// Round 10
// 170.814 us; speedup vs baseline: 1.5640x; 1.0010x over previous
//
#include <hip/hip_runtime.h>
#include <hip/hip_bf16.h>

// DiffAttn: B=4, S=4096, EMB=1024, D=128
//   Q = X@Wq+bq (256 cols = Q1|Q2), K likewise, V = X@Wv+bv (128)
//   out = softmax(Q1K1^T/sqrt(D))@V - lam*softmax(Q2K2^T/sqrt(D))@V
// attn v7: BRANCH-SPLIT blocks — 256 thr = 4 waves x 32q, ONE branch per
// block; grid 256*nsplit -> 2 blocks/CU = two independent barrier domains
// whose QK/softmax/PV phases stagger (breaks the lockstep phase-sum wall).
// LDS 3 x 16KB {K_br[32][256B] rot | V[128][64B] rot}, global_load_lds
// staging w/ pre-rotated source, counted vmcnt(4), raw v_exp_f32 softmax,
// cvt_pk + permlane32_swap P->B-frag.

typedef __attribute__((ext_vector_type(8))) short bf16x8;    // 8 bf16
typedef __attribute__((ext_vector_type(4))) float f32x4;
typedef __attribute__((ext_vector_type(16))) float f32x16;   // 32x32 C/D

#define MFMA16(a, b, c) __builtin_amdgcn_mfma_f32_16x16x32_bf16((a), (b), (c), 0, 0, 0)
#define MFMA32(a, b, c) __builtin_amdgcn_mfma_f32_32x32x16_bf16((a), (b), (c), 0, 0, 0)

typedef const __attribute__((address_space(1))) void gas_void;
typedef __attribute__((address_space(3))) void las_void;
#define GLOAD16(G, L) __builtin_amdgcn_global_load_lds((gas_void*)(G), (las_void*)(L), 16, 0, 0)

__device__ __forceinline__ unsigned short f2bf(float x) {
    union { float f; unsigned u; } v; v.f = x;   // RNE float->bf16
    return (unsigned short)((v.u + 0x7FFFu + ((v.u >> 16) & 1u)) >> 16);
}
__device__ __forceinline__ unsigned pk2bf(float a, float b) {   // v_cvt_pk_bf16_f32
    __hip_bfloat162 h = __float22bfloat162_rn(float2{a, b});
    union { __hip_bfloat162 h2; unsigned u; } cv; cv.h2 = h;
    return cv.u;
}
__device__ __forceinline__ float fexp2(float x) {   // raw v_exp_f32: D = 2^S0
    float r; asm("v_exp_f32 %0, %1" : "=v"(r) : "v"(x)); return r;
}

// ---------------- W transpose + bf16 convert: Wt[640][1024] ----------------
__global__ __launch_bounds__(256) void wtrans_kernel(
    const float* __restrict__ Wq, const float* __restrict__ Wk,
    const float* __restrict__ Wv, unsigned short* __restrict__ Wt) {
    int tid = blockIdx.x * 256 + threadIdx.x;   // 640*1024 total
    int k = tid & 1023, n = tid >> 10;
    float v;
    if (n < 256)      v = Wq[k * 256 + n];
    else if (n < 512) v = Wk[k * 256 + (n - 256)];
    else              v = Wv[k * 128 + (n - 512)];
    Wt[tid] = f2bf(v);
}

// ---------------- QKV projection GEMM ----------------
__global__ __launch_bounds__(256) void proj_kernel(
    const float* __restrict__ X, const unsigned short* __restrict__ Wt,
    const float* __restrict__ bq, const float* __restrict__ bk,
    const float* __restrict__ bv,
    unsigned short* __restrict__ Qs, unsigned short* __restrict__ Kb,
    unsigned short* __restrict__ Vb) {
    __shared__ alignas(16) char lds[16384];   // Xt[128][32]bf16 @0, Wtile @8192
    const int nt = blockIdx.y;
    const int m0 = blockIdx.x * 128;
    const int t = threadIdx.x, w = t >> 6, l = t & 63, c = l & 15, g = l >> 4;
    const int wm = w >> 1, wn = w & 1;
    const unsigned short* Wrow = Wt + (long)(nt * 128) * 1024;

    f32x4 acc[4][4];
    const f32x4 fz = {0.f, 0.f, 0.f, 0.f};
#pragma unroll
    for (int i = 0; i < 4; i++)
#pragma unroll
        for (int j = 0; j < 4; j++) acc[i][j] = fz;

    const int srow = t >> 1, sh = t & 1;
    const int sswz = (srow & 7) << 4;
    for (int k0 = 0; k0 < 1024; k0 += 32) {
        const float* xs = X + (long)(m0 + srow) * 1024 + k0 + sh * 16;
        float4 f0 = *(const float4*)(xs + 0);
        float4 f1 = *(const float4*)(xs + 4);
        float4 f2 = *(const float4*)(xs + 8);
        float4 f3 = *(const float4*)(xs + 12);
        const unsigned short* wsc = Wrow + (long)srow * 1024 + k0 + sh * 16;
        uint4 w0 = *(const uint4*)(wsc + 0);
        uint4 w1 = *(const uint4*)(wsc + 8);
        uint4 xa, xb;
        xa.x = pk2bf(f0.x, f0.y); xa.y = pk2bf(f0.z, f0.w);
        xa.z = pk2bf(f1.x, f1.y); xa.w = pk2bf(f1.z, f1.w);
        xb.x = pk2bf(f2.x, f2.y); xb.y = pk2bf(f2.z, f2.w);
        xb.z = pk2bf(f3.x, f3.y); xb.w = pk2bf(f3.z, f3.w);
        int base = srow * 64 + sh * 32;
        *(uint4*)(lds + ((base + 0) ^ sswz)) = xa;
        *(uint4*)(lds + ((base + 16) ^ sswz)) = xb;
        *(uint4*)(lds + 8192 + ((base + 0) ^ sswz)) = w0;
        *(uint4*)(lds + 8192 + ((base + 16) ^ sswz)) = w1;
        __syncthreads();

        bf16x8 af[4];
#pragma unroll
        for (int am = 0; am < 4; am++) {
            int r_ = wm * 64 + am * 16 + c;
            af[am] = *(const bf16x8*)(lds + ((r_ * 64 + g * 16) ^ ((c & 7) << 4)));
        }
#pragma unroll
        for (int bn = 0; bn < 4; bn++) {
            int r_ = wn * 64 + bn * 16 + c;
            bf16x8 bfr = *(const bf16x8*)(lds + 8192 + ((r_ * 64 + g * 16) ^ ((c & 7) << 4)));
#pragma unroll
            for (int am = 0; am < 4; am++) acc[am][bn] = MFMA16(af[am], bfr, acc[am][bn]);
        }
        __syncthreads();
    }

    // Q scale folds 1/sqrt(128) AND log2(e) so attn softmax is pure exp2.
    const float QSCALE = 0.08838834764831845f * 1.4426950408889634f;
    const float* bias; float scale; unsigned short* outp; int ostride, ocol0, boff;
    if (nt < 2)      { bias = bq; boff = nt * 128;       scale = QSCALE; outp = Qs; ostride = 256; ocol0 = nt * 128; }
    else if (nt < 4) { bias = bk; boff = (nt - 2) * 128; scale = 1.0f;   outp = Kb; ostride = 256; ocol0 = (nt - 2) * 128; }
    else             { bias = bv; boff = 0;              scale = 1.0f;   outp = Vb; ostride = 128; ocol0 = 0; }
#pragma unroll
    for (int bn = 0; bn < 4; bn++) {
        int ncol = wn * 64 + bn * 16 + c;
        float bb = bias[boff + ncol];
#pragma unroll
        for (int am = 0; am < 4; am++) {
#pragma unroll
            for (int r = 0; r < 4; r++) {
                long row = m0 + wm * 64 + am * 16 + 4 * g + r;
                outp[row * ostride + ocol0 + ncol] = f2bf((acc[am][bn][r] + bb) * scale);
            }
        }
    }
}

// ---------------- V transpose: Vt[b][128][4096] ----------------
__global__ __launch_bounds__(256) void vtrans_kernel(
    const unsigned short* __restrict__ Vb, unsigned short* __restrict__ Vt) {
    int tid = blockIdx.x * 256 + threadIdx.x;   // 4*128*4096
    int s = tid & 4095, d = (tid >> 12) & 127, b = tid >> 19;
    Vt[tid] = Vb[(((long)b << 12) + s) * 128 + d];
}

// ---------------- flash diff-attention v7 (branch-split blocks) -----------
// 256 threads = 4 waves, each wave one 32q sub-block, ALL same branch (br =
// block coord). LDS: 3 buffers x 16KB {K_br @0 | V @8192}. Stage 2 ahead,
// vmcnt(4) per iter (tile i ready, i+1 in flight).
__global__ __launch_bounds__(256) void attn3_kernel(
    const unsigned short* __restrict__ Qs, const unsigned short* __restrict__ Kb,
    const unsigned short* __restrict__ Vt,
    float* __restrict__ Po, float* __restrict__ Ps, int nsplit, int ks) {
    __shared__ alignas(16) char lds[49152];
    const int t = threadIdx.x;
    const int w = t >> 6, l = t & 63, r31 = l & 31, hi = l >> 5;

    const int total = gridDim.x;                 // 256*nsplit (div by 8)
    const int lin = (blockIdx.x & 7) * (total >> 3) + (blockIdx.x >> 3);
    const int qb = lin & 31;
    const int g2 = lin >> 5;                     // (b*nsplit+split)*2 + br
    const int br = g2 & 1;
    const int sp = g2 >> 1;
    const int split = sp % nsplit, b = sp / nsplit;

    const long qrow = (long)b * 4096 + qb * 128 + w * 32 + r31;
    bf16x8 qf[8];
    const unsigned short* Qp = Qs + qrow * 256 + br * 128 + hi * 8;
#pragma unroll
    for (int ds = 0; ds < 8; ds++) qf[ds] = *(const bf16x8*)(Qp + ds * 16);

    f32x16 o[4];
    const f32x16 oz = {};
#pragma unroll
    for (int dt = 0; dt < 4; dt++) o[dt] = oz;
    float m = -1e30f, s = 0.f;

    // --- staging geometry (256 thr): LDS[i]=t*16 linear, rotated source ---
    // K call A: rows 0-15, call B: rows 16-31. LDS col=(src+row*16)&255.
    const int krowA = t >> 4;
    const int kcolS = (((t & 15) * 16) - krowA * 16) & 255;
    // V call A: d 0-63, call B: d 64-127. LDS col=(src+((d>>1)&3)*16)&63.
    const int vdA = t >> 2;
    const int vcolS = (((t & 3) * 16) - (((vdA >> 1) & 3) * 16)) & 63;
    const long kbb = (long)b * 4096;
    const char* kSrc0 = (const char*)Kb + (kbb + krowA) * 512 + br * 256 + kcolS;
    const char* vSrc0 = (const char*)Vt + ((long)b * 128 + vdA) * 8192 + vcolS;
    char* dst0 = lds + w * 1024;                 // wave-uniform base

    const int kb0 = split * ks;
    const int nt = ks >> 5;
#define STAGE(KB_, BUF_)                                                       \
    {                                                                          \
        const char* kp_ = kSrc0 + (long)(KB_)*512;                             \
        const char* vp_ = vSrc0 + (long)(KB_)*2;                               \
        char* d_ = dst0 + (BUF_)*16384;                                        \
        GLOAD16(kp_, d_);                                                      \
        GLOAD16(kp_ + 8192, d_ + 4096);                                        \
        GLOAD16(vp_, d_ + 8192);                                               \
        GLOAD16(vp_ + 524288, d_ + 12288);                                     \
    }

    // --- read offsets (loop-invariant) ---
    int kro[8];
#pragma unroll
    for (int ds = 0; ds < 8; ds++)
        kro[ds] = r31 * 256 + ((ds * 32 + hi * 16 + r31 * 16) & 255);
    int vro0[4], vro1[4];
#pragma unroll
    for (int dt = 0; dt < 4; dt++) {
        int vr = dt * 32 + r31, rot = ((vr >> 1) & 3) * 16;
        vro0[dt] = 8192 + vr * 64 + ((hi * 16 + rot) & 63);
        vro1[dt] = 8192 + vr * 64 + ((32 + hi * 16 + rot) & 63);
    }

    STAGE(kb0, 0);
    STAGE(kb0 + 32, 1);
    int cb = 0, sb = 2;   // compute buf = i%3, stage buf = (i+2)%3

    for (int it = 0; it < nt; it++) {
        asm volatile("s_waitcnt vmcnt(4)" ::: "memory");
        __builtin_amdgcn_sched_barrier(0);
        __builtin_amdgcn_s_barrier();
        __builtin_amdgcn_sched_barrier(0);
        {
            int i2 = it + 2;
            int kn = (i2 < nt) ? kb0 + (i2 << 5) : kb0;   // dummy in tail
            STAGE(kn, sb);
        }
        const char* bufp = lds + cb * 16384;

        // ---- QK^T: P^T[key][q], two independent 4-deep chains ----
        f32x16 pa = oz, pb_ = oz;
        __builtin_amdgcn_s_setprio(1);
#pragma unroll
        for (int ds = 0; ds < 4; ds++) {
            bf16x8 kfa = *(const bf16x8*)(bufp + kro[ds]);
            bf16x8 kfb = *(const bf16x8*)(bufp + kro[ds + 4]);
            pa = MFMA32(kfa, qf[ds], pa);
            pb_ = MFMA32(kfb, qf[ds + 4], pb_);
        }
        __builtin_amdgcn_s_setprio(0);
        f32x16 p;
#pragma unroll
        for (int i = 0; i < 16; i++) p[i] = pa[i] + pb_[i];

        // ---- in-register softmax (exp2 domain; defer-max THR=8) ----
        // max3-shaped tree (clang fuses nested fmaxf -> v_max3_f32)
        float m0_ = fmaxf(fmaxf(p[0], p[1]), p[2]);
        float m1_ = fmaxf(fmaxf(p[3], p[4]), p[5]);
        float m2_ = fmaxf(fmaxf(p[6], p[7]), p[8]);
        float m3_ = fmaxf(fmaxf(p[9], p[10]), p[11]);
        float m4_ = fmaxf(fmaxf(p[12], p[13]), p[14]);
        float lmx = fmaxf(fmaxf(fmaxf(fmaxf(m0_, m1_), m2_),
                                fmaxf(m3_, m4_)), p[15]);
        lmx = fmaxf(lmx, __shfl_xor(lmx, 32));
        if (__any(lmx > m + 8.f)) {
            float mn = fmaxf(m, lmx);
            float al = fexp2(m - mn);
            s *= al; m = mn;
#pragma unroll
            for (int dt = 0; dt < 4; dt++) o[dt] *= al;
        }
        float pe[16];
#pragma unroll
        for (int i = 0; i < 16; i++) pe[i] = fexp2(p[i] - m);
        float s0 = (pe[0] + pe[1]) + (pe[2] + pe[3]);
        float s1 = (pe[4] + pe[5]) + (pe[6] + pe[7]);
        float s2 = (pe[8] + pe[9]) + (pe[10] + pe[11]);
        float s3 = (pe[12] + pe[13]) + (pe[14] + pe[15]);
        float ps_ = (s0 + s1) + (s2 + s3);
        ps_ += __shfl_xor(ps_, 32);
        s += ps_;

        // ---- P -> PV B-fragments (cvt_pk + permlane32_swap) ----
        unsigned cA = pk2bf(pe[0], pe[1]), cB = pk2bf(pe[2], pe[3]);
        unsigned cC = pk2bf(pe[4], pe[5]), cD = pk2bf(pe[6], pe[7]);
        asm volatile("v_permlane32_swap_b32 %0, %1" : "+v"(cA), "+v"(cC));
        asm volatile("v_permlane32_swap_b32 %0, %1" : "+v"(cB), "+v"(cD));
        unsigned dA = pk2bf(pe[8], pe[9]), dB = pk2bf(pe[10], pe[11]);
        unsigned dC = pk2bf(pe[12], pe[13]), dD = pk2bf(pe[14], pe[15]);
        asm volatile("v_permlane32_swap_b32 %0, %1" : "+v"(dA), "+v"(dC));
        asm volatile("v_permlane32_swap_b32 %0, %1" : "+v"(dB), "+v"(dD));
        union { uint4 u; bf16x8 v; } pb0, pb1;
        pb0.u = uint4{cA, cB, cC, cD};   // keys 0-15
        pb1.u = uint4{dA, dB, dC, dD};   // keys 16-31

        // ---- PV: O^T[d][q] += V^T-frag x PB ----
        __builtin_amdgcn_s_setprio(1);
#pragma unroll
        for (int dt = 0; dt < 4; dt++) {
            bf16x8 vf0 = *(const bf16x8*)(bufp + vro0[dt]);
            bf16x8 vf1 = *(const bf16x8*)(bufp + vro1[dt]);
            o[dt] = MFMA32(vf0, pb0.v, o[dt]);
            o[dt] = MFMA32(vf1, pb1.v, o[dt]);
        }
        __builtin_amdgcn_s_setprio(0);
        cb = (cb == 2) ? 0 : cb + 1;
        sb = (sb == 2) ? 0 : sb + 1;
    }
    asm volatile("s_waitcnt vmcnt(0)" ::: "memory");

    // ---- epilogue: per-branch partials ----
    float* po = Po + ((qrow * nsplit + split) * 2 + br) * 128;
#pragma unroll
    for (int dt = 0; dt < 4; dt++) {
#pragma unroll
        for (int rg = 0; rg < 4; rg++) {
            float4 v;   // d = dt*32 + rg*8 + hi*4 + j
            v.x = o[dt][rg * 4 + 0];
            v.y = o[dt][rg * 4 + 1];
            v.z = o[dt][rg * 4 + 2];
            v.w = o[dt][rg * 4 + 3];
            *(float4*)(po + dt * 32 + rg * 8 + hi * 4) = v;
        }
    }
    if (hi == 0)
        *(float2*)(Ps + (qrow * nsplit + split) * 4 + br * 2) = float2{m, s};
#undef STAGE
}

// ---------------- split combine ----------------
__global__ __launch_bounds__(256) void combine_kernel(
    const float* __restrict__ Po, const float* __restrict__ Ps,
    const float* __restrict__ lam_p, float* __restrict__ out, int nsplit) {
    int tid = blockIdx.x * 256 + threadIdx.x;   // 16384 q * 32 threads
    int q = tid >> 5, dq = (tid & 31) * 4;
    float M1 = -1e30f, M2 = -1e30f;
    for (int s = 0; s < nsplit; s++) {
        float4 st = *(const float4*)(Ps + (long)(q * nsplit + s) * 4);
        M1 = fmaxf(M1, st.x); M2 = fmaxf(M2, st.z);
    }
    float S1 = 0.f, S2 = 0.f;
    float a0 = 0.f, a1 = 0.f, a2 = 0.f, a3 = 0.f;
    float b0 = 0.f, b1 = 0.f, b2 = 0.f, b3 = 0.f;
    for (int s = 0; s < nsplit; s++) {
        float4 st = *(const float4*)(Ps + (long)(q * nsplit + s) * 4);
        float w1 = fexp2(st.x - M1), w2 = fexp2(st.z - M2);
        S1 += st.y * w1; S2 += st.w * w2;
        const float* p1 = Po + (((long)q * nsplit + s) * 2 + 0) * 128 + dq;
        const float* p2 = Po + (((long)q * nsplit + s) * 2 + 1) * 128 + dq;
        float4 v1 = *(const float4*)p1;
        float4 v2 = *(const float4*)p2;
        a0 += v1.x * w1; a1 += v1.y * w1; a2 += v1.z * w1; a3 += v1.w * w1;
        b0 += v2.x * w2; b1 += v2.y * w2; b2 += v2.z * w2; b3 += v2.w * w2;
    }
    float lam = *lam_p;
    float i1 = 1.f / S1, i2 = lam / S2;
    float4 v;
    v.x = a0 * i1 - b0 * i2;
    v.y = a1 * i1 - b1 * i2;
    v.z = a2 * i1 - b2 * i2;
    v.w = a3 * i1 - b3 * i2;
    *(float4*)(out + (long)q * 128 + dq) = v;
}

extern "C" void kernel_launch(void* const* d_in, const int* in_sizes, int n_in,
                              void* d_out, int out_size, void* d_ws, size_t ws_size,
                              hipStream_t stream) {
    const float* X   = (const float*)d_in[0];
    const float* lam = (const float*)d_in[1];
    const float* Wq  = (const float*)d_in[2];
    const float* bq  = (const float*)d_in[3];
    const float* Wk  = (const float*)d_in[4];
    const float* bk  = (const float*)d_in[5];
    const float* Wv  = (const float*)d_in[6];
    const float* bv  = (const float*)d_in[7];
    char* ws = (char*)d_ws;
    // ws: Qs 8M | Kb 8M | Vb 4M | Vt 4M | Wt 1.25M | @26M: Po, Ps
    unsigned short* Qs = (unsigned short*)(ws);
    unsigned short* Kb = (unsigned short*)(ws + (8u << 20));
    unsigned short* Vb = (unsigned short*)(ws + (16u << 20));
    unsigned short* Vt = (unsigned short*)(ws + (20u << 20));
    unsigned short* Wt = (unsigned short*)(ws + (24u << 20));
    const size_t base = (size_t)26 << 20;
    const size_t NQ = 16384;
    int nsplit = 1;
    if (ws_size >= base + NQ * 4 * 2 * 128 * 4 + NQ * 4 * 4 * 4)      nsplit = 4;
    else if (ws_size >= base + NQ * 2 * 2 * 128 * 4 + NQ * 2 * 4 * 4) nsplit = 2;
    float* Po = (float*)(ws + base);
    float* Ps = (float*)(ws + base + NQ * (size_t)nsplit * 2 * 128 * 4);

    wtrans_kernel<<<2560, 256, 0, stream>>>(Wq, Wk, Wv, Wt);
    proj_kernel<<<dim3(128, 5), 256, 0, stream>>>(X, Wt, bq, bk, bv, Qs, Kb, Vb);
    vtrans_kernel<<<8192, 256, 0, stream>>>(Vb, Vt);
    attn3_kernel<<<256 * nsplit, 256, 0, stream>>>(Qs, Kb, Vt, Po, Ps,
                                                   nsplit, 4096 / nsplit);
    combine_kernel<<<2048, 256, 0, stream>>>(Po, Ps, lam, (float*)d_out, nsplit);
}